// Round 1
// baseline (227.521 us; speedup 1.0000x reference)
//
#include <hip/hip_runtime.h>
#include <stdint.h>

#define DI static __device__ __forceinline__

typedef __attribute__((ext_vector_type(8))) short bh8;   // 8 x bf16 (4 VGPRs)
typedef __attribute__((ext_vector_type(4))) float f4;    // MFMA accumulator

DI short f2bf(float f) {             // fp32 -> bf16 (RNE)
  unsigned u = __float_as_uint(f);
  u += 0x7fffu + ((u >> 16) & 1u);
  return (short)(u >> 16);
}

DI void gll16(const void* g, void* l) {  // 16B global -> LDS async
  __builtin_amdgcn_global_load_lds(
      (const __attribute__((address_space(1))) unsigned int*)g,
      (__attribute__((address_space(3))) unsigned int*)l, 16, 0, 0);
}

DI f4 mfma16(bh8 a, bh8 b, f4 c) {
  return __builtin_amdgcn_mfma_f32_16x16x32_bf16(a, b, c, 0, 0, 0);
}

DI bh8 ld8(const short* p) { return *(const bh8*)p; }

// ---------------------------------------------------------------------------
// LayerNorm over C=512 with fused [B,C,T] -> [token, C] transpose, bf16 out.
// block = 256 threads, handles 16 tokens of one batch. z: 0=kv, 1=q.
// ---------------------------------------------------------------------------
__global__ __launch_bounds__(256) void ln_k(
    const float* __restrict__ kv, const float* __restrict__ qi,
    const float* __restrict__ kw, const float* __restrict__ kbv,
    const float* __restrict__ qw, const float* __restrict__ qbv,
    short* __restrict__ kvn, short* __restrict__ qn)
{
  __shared__ float xs[512][17];          // [c][t], pad 17 -> conflict-free
  __shared__ float smean[16], srstd[16];
  int which = blockIdx.z;
  const float* x = which ? qi : kv;
  const float* w = which ? qw : kw;
  const float* bb = which ? qbv : kbv;
  short* o = which ? qn : kvn;
  int b = blockIdx.y;
  int t0 = blockIdx.x << 4;
  int tid = threadIdx.x;
  const float* xb = x + ((size_t)b << 19) + (size_t)t0;   // b*512*1024 + t0
  for (int idx = tid; idx < 512 * 16; idx += 256) {
    int c = idx >> 4, t = idx & 15;
    xs[c][t] = xb[((size_t)c << 10) + t];
  }
  __syncthreads();
  {
    int t = tid >> 4, cp = tid & 15;     // 16 partials per token, in-wave
    float s = 0.f, s2 = 0.f;
#pragma unroll
    for (int k = 0; k < 32; k++) {
      float v = xs[cp + (k << 4)][t];
      s += v; s2 += v * v;
    }
#pragma unroll
    for (int m = 1; m < 16; m <<= 1) {
      s  += __shfl_xor(s,  m);
      s2 += __shfl_xor(s2, m);
    }
    if (cp == 0) {
      float mean = s * (1.f / 512.f);
      float var  = s2 * (1.f / 512.f) - mean * mean;
      smean[t] = mean;
      srstd[t] = rsqrtf(var + 1e-5f);
    }
  }
  __syncthreads();
  for (int idx = tid; idx < 512 * 16; idx += 256) {
    int t = idx >> 9, c = idx & 511;
    float v = (xs[c][t] - smean[t]) * srstd[t] * w[c] + bb[c];
    o[(((size_t)(b << 10) + t0 + t) << 9) + c] = f2bf(v);
  }
}

// ---------------------------------------------------------------------------
// Weight transpose + fp32->bf16: Wt[co][ci] = W[ci][co]. z selects weight.
// ---------------------------------------------------------------------------
__global__ __launch_bounds__(256) void wt_k(
    const float* __restrict__ Wk, const float* __restrict__ Wq,
    const float* __restrict__ Wv, const float* __restrict__ Wp,
    short* __restrict__ Wt)
{
  __shared__ float ts[32][33];
  int z = blockIdx.z;
  const float* w = (z == 0) ? Wk : (z == 1) ? Wq : (z == 2) ? Wv : Wp;
  short* o = Wt + ((size_t)z << 18);
  int c0 = blockIdx.x << 5, r0 = blockIdx.y << 5;
  int tx = threadIdx.x & 31, ty = threadIdx.x >> 5;   // 32 x 8
#pragma unroll
  for (int k = 0; k < 32; k += 8)
    ts[ty + k][tx] = w[((size_t)(r0 + ty + k) << 9) + c0 + tx];
  __syncthreads();
#pragma unroll
  for (int k = 0; k < 32; k += 8)
    o[((size_t)(c0 + ty + k) << 9) + r0 + tx] = f2bf(ts[tx][ty + k]);
}

// ---------------------------------------------------------------------------
// bf16 GEMM, m97 structure: C = A[M,512] x Bt[N,512]^T, 128x128 tile, BK=32.
// MODE 0: C[token, c] -> bf16 [b,h,t,d] + bias[n]          (K,Q projections)
// MODE 1: C[c, token] -> bf16 [b,h,d,t] (V^T) + bias[m]    (V projection)
// MODE 2: C[c, token] -> fp32 out[b,c,t] + bias[m] + resid (output proj)
// ---------------------------------------------------------------------------
template <int MODE>
__global__ __launch_bounds__(256) void gemm_k(
    const short* __restrict__ A, const short* __restrict__ Bt,
    const float* __restrict__ bias, void* __restrict__ outp,
    const float* __restrict__ resid)
{
  __shared__ short As[128 * 32];
  __shared__ short Bs[128 * 32];
  int m0 = blockIdx.x << 7, n0 = blockIdx.y << 7;
  int tid = threadIdx.x;
  int lane = tid & 63, wid = tid >> 6;
  int r = lane & 15, g = lane >> 4;
  int wrow = (wid >> 1) << 6, wcol = (wid & 1) << 6;
  f4 acc[4][4];
#pragma unroll
  for (int i = 0; i < 4; i++)
#pragma unroll
    for (int j = 0; j < 4; j++) {
      acc[i][j][0] = 0.f; acc[i][j][1] = 0.f;
      acc[i][j][2] = 0.f; acc[i][j][3] = 0.f;
    }
  const short* Ag = A  + ((size_t)(m0 + (tid >> 2)) << 9) + ((tid & 3) << 3);
  const short* Bg = Bt + ((size_t)(n0 + (tid >> 2)) << 9) + ((tid & 3) << 3);
  short* Asl = As + tid * 8;
  short* Bsl = Bs + tid * 8;
  for (int k0 = 0; k0 < 512; k0 += 32) {
    __syncthreads();
    gll16(Ag + k0,             Asl);
    gll16(Ag + k0 + 64 * 512,  Asl + 2048);
    gll16(Bg + k0,             Bsl);
    gll16(Bg + k0 + 64 * 512,  Bsl + 2048);
    __syncthreads();
    bh8 a[4], b[4];
#pragma unroll
    for (int i = 0; i < 4; i++)
      a[i] = ld8(As + ((wrow + (i << 4) + r) << 5) + (g << 3));
#pragma unroll
    for (int j = 0; j < 4; j++)
      b[j] = ld8(Bs + ((wcol + (j << 4) + r) << 5) + (g << 3));
#pragma unroll
    for (int i = 0; i < 4; i++)
#pragma unroll
      for (int j = 0; j < 4; j++)
        acc[i][j] = mfma16(a[i], b[j], acc[i][j]);
  }
  // epilogue: C/D layout col = lane&15, row = (lane>>4)*4 + reg
#pragma unroll
  for (int i = 0; i < 4; i++) {
#pragma unroll
    for (int j = 0; j < 4; j++) {
      int mm = m0 + wrow + (i << 4) + (g << 2);
      int nn = n0 + wcol + (j << 4) + r;
      if (MODE == 0) {
        float bv = bias[nn];
        int h = nn >> 6, d = nn & 63;
        short* ob = (short*)outp;
#pragma unroll
        for (int q = 0; q < 4; q++) {
          int m = mm + q;
          int bb = m >> 10, t = m & 1023;
          ob[((((size_t)(bb * 8 + h)) << 10) + t) * 64 + d] =
              f2bf(acc[i][j][q] + bv);
        }
      } else if (MODE == 1) {
        int bb = nn >> 10, t = nn & 1023;
        short* ob = (short*)outp;
#pragma unroll
        for (int q = 0; q < 4; q++) {
          int m = mm + q;
          int h = m >> 6, d = m & 63;
          ob[((((size_t)(bb * 8 + h)) << 6) + d) * 1024 + t] =
              f2bf(acc[i][j][q] + bias[m]);
        }
      } else {
        int bb = nn >> 10, t = nn & 1023;
        float* ob = (float*)outp;
#pragma unroll
        for (int q = 0; q < 4; q++) {
          int m = mm + q;
          size_t ad = ((((size_t)bb << 9) + m) << 10) + t;
          ob[ad] = acc[i][j][q] + bias[m] + resid[ad];
        }
      }
    }
  }
}

// ---------------------------------------------------------------------------
// Flash attention. block = 256 (4 waves), one (b, h, 128-row q-tile).
// q,k: [b,h,t,64] bf16; v: [b,h,64,t] bf16 (pre-transposed). y -> [token,512].
// K rows staged with perm pi(c) = (c%16)*8 + c/16 so the P->LDS store is a
// single ds_write_b128 per (row,reg) and V staging stays canonical.
// ---------------------------------------------------------------------------
__global__ __launch_bounds__(256) void attn_k(
    const short* __restrict__ qb, const short* __restrict__ kb,
    const short* __restrict__ vtb, short* __restrict__ yo)
{
  __shared__ short Ks[2 * 128 * 32];   // [d-half][c][32]
  __shared__ short Vs[4 * 64 * 32];    // [t-quarter][d][32]
  __shared__ short Ps[4 * 128 * 32];   // [t-quarter][row][32], xor-swizzled
  int qt0 = blockIdx.x << 7;
  int h = blockIdx.y, b = blockIdx.z;
  int tid = threadIdx.x, lane = tid & 63, wid = tid >> 6;
  int r = lane & 15, g = lane >> 4;
  size_t bh = (size_t)(b * 8 + h);
  const short* Qg = qb  + ((bh << 10) + qt0) * 64;
  const short* Kg = kb  + (bh << 10) * 64;
  const short* Vg = vtb + (bh << 6) * 1024;

  // Q fragments straight to registers (reused all 8 chunks)
  bh8 qf[2][2];
#pragma unroll
  for (int i = 0; i < 2; i++)
#pragma unroll
    for (int ks = 0; ks < 2; ks++)
      qf[i][ks] = *(const bh8*)(Qg +
          ((size_t)((wid << 5) + (i << 4) + r) << 6) + (ks << 5) + (g << 3));

  f4 oac[2][4];
  float mi[2][4], li[2][4];
#pragma unroll
  for (int i = 0; i < 2; i++)
#pragma unroll
    for (int jn = 0; jn < 4; jn++) {
      oac[i][jn][0] = 0.f; oac[i][jn][1] = 0.f;
      oac[i][jn][2] = 0.f; oac[i][jn][3] = 0.f;
    }
#pragma unroll
  for (int i = 0; i < 2; i++)
#pragma unroll
    for (int q = 0; q < 4; q++) { mi[i][q] = -1e30f; li[i][q] = 0.f; }

  for (int ck = 0; ck < 8; ck++) {
    __syncthreads();                       // previous chunk's LDS readers done
    {
      const short* Kc = Kg + ((size_t)(ck << 7) << 6);
#pragma unroll
      for (int it = 0; it < 4; it++) {
        int c = ((it & 1) << 6) + (tid >> 2);
        int half = it >> 1;
        int pc = ((c & 15) << 3) + (c >> 4);       // pi(c)
        gll16(Kc + ((size_t)pc << 6) + (half << 5) + ((tid & 3) << 3),
              Ks + it * 2048 + tid * 8);
      }
      const short* Vc = Vg + (ck << 7);
#pragma unroll
      for (int it = 0; it < 4; it++) {
        gll16(Vc + ((size_t)(tid >> 2) << 10) + (it << 5) + ((tid & 3) << 3),
              Vs + it * 2048 + tid * 8);
      }
    }
    __syncthreads();

    // S = Q K^T (perm-space columns)
    f4 s[2][8];
#pragma unroll
    for (int i = 0; i < 2; i++)
#pragma unroll
      for (int j = 0; j < 8; j++) {
        s[i][j][0] = 0.f; s[i][j][1] = 0.f; s[i][j][2] = 0.f; s[i][j][3] = 0.f;
      }
#pragma unroll
    for (int ks = 0; ks < 2; ks++) {
#pragma unroll
      for (int j = 0; j < 8; j++) {
        bh8 bk8 = ld8(Ks + ks * 4096 + (((j << 4) + r) << 5) + (g << 3));
#pragma unroll
        for (int i = 0; i < 2; i++)
          s[i][j] = mfma16(qf[i][ks], bk8, s[i][j]);
      }
    }

    // online softmax (base-2): z = S * log2(e)/8
    const float csc = 0.18033688011112042f;
#pragma unroll
    for (int i = 0; i < 2; i++) {
#pragma unroll
      for (int q = 0; q < 4; q++) {
        float mv = s[i][0][q];
#pragma unroll
        for (int j = 1; j < 8; j++) mv = fmaxf(mv, s[i][j][q]);
#pragma unroll
        for (int msk = 1; msk < 16; msk <<= 1)
          mv = fmaxf(mv, __shfl_xor(mv, msk));
        float mnew = fmaxf(mi[i][q], mv * csc);
        float alpha = exp2f(mi[i][q] - mnew);
        mi[i][q] = mnew;
        float sum = 0.f;
#pragma unroll
        for (int j = 0; j < 8; j++) {
          float p = exp2f(s[i][j][q] * csc - mnew);
          s[i][j][q] = p;
          sum += p;
        }
#pragma unroll
        for (int msk = 1; msk < 16; msk <<= 1)
          sum += __shfl_xor(sum, msk);
        li[i][q] = li[i][q] * alpha + sum;
#pragma unroll
        for (int jn = 0; jn < 4; jn++) oac[i][jn][q] *= alpha;
      }
      // pack P rows: lane's 8 cols {j*16+r} land contiguous at p = r*8+j
#pragma unroll
      for (int q = 0; q < 4; q++) {
        bh8 pk;
#pragma unroll
        for (int j = 0; j < 8; j++) pk[j] = f2bf(s[i][j][q]);
        int row = (wid << 5) + (i << 4) + (g << 2) + q;
        int ec = (r & 3) ^ ((row >> 2) & 3);        // bank swizzle
        *(bh8*)(Ps + ((r >> 2) << 12) + (row << 5) + (ec << 3)) = pk;
      }
    }

    // O += P V (wave reads only its own P rows -> no barrier needed)
#pragma unroll
    for (int ks = 0; ks < 4; ks++) {
      bh8 ap[2];
#pragma unroll
      for (int i = 0; i < 2; i++) {
        int row = (wid << 5) + (i << 4) + r;
        int ec = g ^ ((row >> 2) & 3);
        ap[i] = ld8(Ps + (ks << 12) + (row << 5) + (ec << 3));
      }
#pragma unroll
      for (int jn = 0; jn < 4; jn++) {
        bh8 bv8 = ld8(Vs + (ks << 11) + (((jn << 4) + r) << 5) + (g << 3));
#pragma unroll
        for (int i = 0; i < 2; i++)
          oac[i][jn] = mfma16(ap[i], bv8, oac[i][jn]);
      }
    }
  }

  // epilogue: y[token, h*64+d] bf16
#pragma unroll
  for (int i = 0; i < 2; i++) {
#pragma unroll
    for (int q = 0; q < 4; q++) {
      float inv = 1.f / li[i][q];
      int trow = qt0 + (wid << 5) + (i << 4) + (g << 2) + q;
      size_t base = (((size_t)(b << 10) + trow) << 9) + (h << 6);
#pragma unroll
      for (int jn = 0; jn < 4; jn++)
        yo[base + (jn << 4) + r] = f2bf(oac[i][jn][q] * inv);
    }
  }
}

// ---------------------------------------------------------------------------
extern "C" void kernel_launch(void* const* d_in, const int* in_sizes, int n_in,
                              void* d_out, int out_size, void* d_ws, size_t ws_size,
                              hipStream_t stream)
{
  const float* q    = (const float*)d_in[0];
  const float* kv   = (const float*)d_in[1];
  const float* lnkw = (const float*)d_in[2];
  const float* lnkb = (const float*)d_in[3];
  const float* lnqw = (const float*)d_in[4];
  const float* lnqb = (const float*)d_in[5];
  const float* Wk   = (const float*)d_in[6];
  const float* bk   = (const float*)d_in[7];
  const float* Wq   = (const float*)d_in[8];
  const float* bq   = (const float*)d_in[9];
  const float* Wv   = (const float*)d_in[10];
  const float* bv   = (const float*)d_in[11];
  const float* Wp   = (const float*)d_in[12];
  const float* bp   = (const float*)d_in[13];

  char* ws = (char*)d_ws;
  const size_t SZ = (size_t)8192 * 512 * 2;      // 8 MiB per activation buffer
  short* buf0 = (short*)(ws);                    // kv_n, later reused for y
  short* qn   = (short*)(ws + SZ);
  short* kbuf = (short*)(ws + 2 * SZ);
  short* qbuf = (short*)(ws + 3 * SZ);
  short* vtb  = (short*)(ws + 4 * SZ);
  short* Wt   = (short*)(ws + 5 * SZ);           // 4 x 512x512 bf16 = 2 MiB
  if (ws_size < 5 * SZ + 4 * 512 * 512 * 2) return;   // need 42 MiB scratch

  wt_k<<<dim3(16, 16, 4), 256, 0, stream>>>(Wk, Wq, Wv, Wp, Wt);
  ln_k<<<dim3(64, 8, 2), 256, 0, stream>>>(kv, q, lnkw, lnkb, lnqw, lnqb,
                                           buf0, qn);
  gemm_k<0><<<dim3(64, 4), 256, 0, stream>>>(buf0, Wt,            bk, kbuf, nullptr);
  gemm_k<0><<<dim3(64, 4), 256, 0, stream>>>(qn,   Wt + (1 << 18), bq, qbuf, nullptr);
  gemm_k<1><<<dim3(4, 64), 256, 0, stream>>>(Wt + (2 << 18), buf0, bv, vtb, nullptr);
  attn_k<<<dim3(8, 8, 8), 256, 0, stream>>>(qbuf, kbuf, vtb, buf0);
  gemm_k<2><<<dim3(4, 64), 256, 0, stream>>>(Wt + (3 << 18), buf0, bp, d_out, kv);
}

// Round 2
// 184.258 us; speedup vs baseline: 1.2348x; 1.2348x over previous
//
#include <hip/hip_runtime.h>
#include <stdint.h>

#define DI static __device__ __forceinline__

typedef __attribute__((ext_vector_type(8))) short bh8;   // 8 x bf16 (4 VGPRs)
typedef __attribute__((ext_vector_type(4))) float f4;    // MFMA accumulator
typedef __attribute__((ext_vector_type(4))) unsigned int u4;

DI short f2bf(float f) {             // fp32 -> bf16 (RNE)
  unsigned u = __float_as_uint(f);
  u += 0x7fffu + ((u >> 16) & 1u);
  return (short)(u >> 16);
}

DI unsigned pkbf(float a, float b) { // [bf16(a) | bf16(b)<<16], round-half-up
  unsigned ua = __float_as_uint(a) + 0x8000u;
  unsigned ub = __float_as_uint(b) + 0x8000u;
  return __builtin_amdgcn_perm(ub, ua, 0x07060302u);
}

DI void gll16(const void* g, void* l) {  // 16B global -> LDS async
  __builtin_amdgcn_global_load_lds(
      (const __attribute__((address_space(1))) unsigned int*)g,
      (__attribute__((address_space(3))) unsigned int*)l, 16, 0, 0);
}

DI f4 mfma16(bh8 a, bh8 b, f4 c) {
  return __builtin_amdgcn_mfma_f32_16x16x32_bf16(a, b, c, 0, 0, 0);
}

DI bh8 ld8(const short* p) { return *(const bh8*)p; }

// ---------------------------------------------------------------------------
// LayerNorm over C=512, fused [B,C,T] -> [token,C] transpose, bf16 out.
// Vectorized: float4 global loads, LDS [t][c] layout, uint2 (short4) stores.
// ---------------------------------------------------------------------------
__global__ __launch_bounds__(256) void ln_k(
    const float* __restrict__ kv, const float* __restrict__ qi,
    const float* __restrict__ kw, const float* __restrict__ kbv,
    const float* __restrict__ qw, const float* __restrict__ qbv,
    short* __restrict__ kvn, short* __restrict__ qn)
{
  __shared__ float xs[16][516];          // [t][c], row stride 516 (16B aligned)
  __shared__ float smean[16], srstd[16];
  int which = blockIdx.z;
  const float* x = which ? qi : kv;
  const float* w = which ? qw : kw;
  const float* bb = which ? qbv : kbv;
  short* o = which ? qn : kvn;
  int b = blockIdx.y;
  int t0 = blockIdx.x << 4;
  int tid = threadIdx.x;
  const float* xb = x + ((size_t)b << 19) + (size_t)t0;
  // phase 1: [c][t] float4 loads -> xs[t][c]
#pragma unroll
  for (int k = 0; k < 8; k++) {
    int idx = (k << 8) + tid;            // 0..2047
    int c = idx >> 2, tt = (idx & 3) << 2;
    float4 v = *(const float4*)(xb + ((size_t)c << 10) + tt);
    xs[tt + 0][c] = v.x; xs[tt + 1][c] = v.y;
    xs[tt + 2][c] = v.z; xs[tt + 3][c] = v.w;
  }
  __syncthreads();
  // phase 2: per-token mean/var; lane (t, cp) sums c = cp*4 + 64k
  {
    int t = tid >> 4, cp = tid & 15;
    float s = 0.f, s2 = 0.f;
#pragma unroll
    for (int k = 0; k < 8; k++) {
      float4 v = *(const float4*)&xs[t][(cp << 2) + (k << 6)];
      s  += v.x + v.y + v.z + v.w;
      s2 += v.x * v.x + v.y * v.y + v.z * v.z + v.w * v.w;
    }
#pragma unroll
    for (int m = 1; m < 16; m <<= 1) {
      s  += __shfl_xor(s,  m);
      s2 += __shfl_xor(s2, m);
    }
    if (cp == 0) {
      float mean = s * (1.f / 512.f);
      float var  = s2 * (1.f / 512.f) - mean * mean;
      smean[t] = mean;
      srstd[t] = rsqrtf(var + 1e-5f);
    }
  }
  __syncthreads();
  // phase 3: normalize 4 consecutive c, pack to short4
#pragma unroll
  for (int k = 0; k < 8; k++) {
    int idx = (k << 8) + tid;
    int t = idx >> 7, c = (idx & 127) << 2;
    float4 v = *(const float4*)&xs[t][c];
    float4 wv = *(const float4*)(w + c);
    float4 bv4 = *(const float4*)(bb + c);
    float mu = smean[t], rs = srstd[t];
    float r0 = (v.x - mu) * rs * wv.x + bv4.x;
    float r1 = (v.y - mu) * rs * wv.y + bv4.y;
    float r2 = (v.z - mu) * rs * wv.z + bv4.z;
    float r3 = (v.w - mu) * rs * wv.w + bv4.w;
    uint2 pk; pk.x = pkbf(r0, r1); pk.y = pkbf(r2, r3);
    *(uint2*)(o + (((size_t)(b << 10) + t0 + t) << 9) + c) = pk;
  }
}

// ---------------------------------------------------------------------------
// Weight transpose + fp32->bf16: Wt[co][ci] = W[ci][co]. z selects weight.
// ---------------------------------------------------------------------------
__global__ __launch_bounds__(256) void wt_k(
    const float* __restrict__ Wk, const float* __restrict__ Wq,
    const float* __restrict__ Wv, const float* __restrict__ Wp,
    short* __restrict__ Wt)
{
  __shared__ float ts[32][33];
  int z = blockIdx.z;
  const float* w = (z == 0) ? Wk : (z == 1) ? Wq : (z == 2) ? Wv : Wp;
  short* o = Wt + ((size_t)z << 18);
  int c0 = blockIdx.x << 5, r0 = blockIdx.y << 5;
  int tx = threadIdx.x & 31, ty = threadIdx.x >> 5;   // 32 x 8
#pragma unroll
  for (int k = 0; k < 32; k += 8)
    ts[ty + k][tx] = w[((size_t)(r0 + ty + k) << 9) + c0 + tx];
  __syncthreads();
#pragma unroll
  for (int k = 0; k < 32; k += 8)
    o[((size_t)(c0 + ty + k) << 9) + r0 + tx] = f2bf(ts[tx][ty + k]);
}

// ---------------------------------------------------------------------------
// Fused K/Q/V projection GEMM. 128x128 tile, BK=32, grid (64,4,3).
// z=0: kbuf = ln_kv @ Wk  -> bf16 [b,h,t,d]
// z=1: qbuf = ln_q  @ Wq  -> bf16 [b,h,t,d]
// z=2: vtb  = (ln_kv @ Wv)^T -> bf16 [b,h,d,t]   (A=Wv^T, B=ln_kv)
// ---------------------------------------------------------------------------
__global__ __launch_bounds__(256) void gemm_qkv_k(
    const short* __restrict__ kvn, const short* __restrict__ qn,
    const short* __restrict__ Wt,
    const float* __restrict__ bk, const float* __restrict__ bq,
    const float* __restrict__ bv,
    short* __restrict__ kbuf, short* __restrict__ qbuf,
    short* __restrict__ vtb)
{
  __shared__ short As[128 * 32];
  __shared__ short Bs[128 * 32];
  int z = blockIdx.z;
  const short* A; const short* Bt; const float* bias; short* outp;
  int m0, n0;
  if (z == 0)      { A = kvn;            Bt = Wt;            bias = bk; outp = kbuf; }
  else if (z == 1) { A = qn;             Bt = Wt + (1 << 18); bias = bq; outp = qbuf; }
  else             { A = Wt + (2 << 18); Bt = kvn;            bias = bv; outp = vtb; }
  if (z == 2) { m0 = blockIdx.y << 7; n0 = blockIdx.x << 7; }
  else        { m0 = blockIdx.x << 7; n0 = blockIdx.y << 7; }
  int tid = threadIdx.x;
  int lane = tid & 63, wid = tid >> 6;
  int r = lane & 15, g = lane >> 4;
  int wrow = (wid >> 1) << 6, wcol = (wid & 1) << 6;
  f4 acc[4][4];
#pragma unroll
  for (int i = 0; i < 4; i++)
#pragma unroll
    for (int j = 0; j < 4; j++) {
      acc[i][j][0] = 0.f; acc[i][j][1] = 0.f;
      acc[i][j][2] = 0.f; acc[i][j][3] = 0.f;
    }
  const short* Ag = A  + ((size_t)(m0 + (tid >> 2)) << 9) + ((tid & 3) << 3);
  const short* Bg = Bt + ((size_t)(n0 + (tid >> 2)) << 9) + ((tid & 3) << 3);
  short* Asl = As + tid * 8;
  short* Bsl = Bs + tid * 8;
  for (int k0 = 0; k0 < 512; k0 += 32) {
    __syncthreads();
    gll16(Ag + k0,            Asl);
    gll16(Ag + k0 + 64 * 512, Asl + 2048);
    gll16(Bg + k0,            Bsl);
    gll16(Bg + k0 + 64 * 512, Bsl + 2048);
    __syncthreads();
    bh8 a[4], b[4];
#pragma unroll
    for (int i = 0; i < 4; i++)
      a[i] = ld8(As + ((wrow + (i << 4) + r) << 5) + (g << 3));
#pragma unroll
    for (int j = 0; j < 4; j++)
      b[j] = ld8(Bs + ((wcol + (j << 4) + r) << 5) + (g << 3));
#pragma unroll
    for (int i = 0; i < 4; i++)
#pragma unroll
      for (int j = 0; j < 4; j++)
        acc[i][j] = mfma16(a[i], b[j], acc[i][j]);
  }
  // epilogue: C/D layout col = lane&15, row = (lane>>4)*4 + reg
#pragma unroll
  for (int i = 0; i < 4; i++) {
#pragma unroll
    for (int j = 0; j < 4; j++) {
      int mm = m0 + wrow + (i << 4) + (g << 2);
      int nn = n0 + wcol + (j << 4) + r;
      if (z != 2) {
        float bvv = bias[nn];
        int h = nn >> 6, d = nn & 63;
#pragma unroll
        for (int q = 0; q < 4; q++) {
          int m = mm + q;
          int bb = m >> 10, t = m & 1023;
          outp[((((size_t)(bb * 8 + h)) << 10) + t) * 64 + d] =
              f2bf(acc[i][j][q] + bvv);
        }
      } else {
        int bb = nn >> 10, t = nn & 1023;
#pragma unroll
        for (int q = 0; q < 4; q++) {
          int m = mm + q;
          int h = m >> 6, d = m & 63;
          outp[((((size_t)(bb * 8 + h)) << 6) + d) * 1024 + t] =
              f2bf(acc[i][j][q] + bias[m]);
        }
      }
    }
  }
}

// ---------------------------------------------------------------------------
// Output projection: C[c,token] = Wp^T @ y^T, 64x128 tile, grid (64,8).
// out fp32 [b,c,t] = C + bias[c] + resid; x = n-tile for XCD locality.
// ---------------------------------------------------------------------------
__global__ __launch_bounds__(256) void gemm_proj_k(
    const short* __restrict__ A, const short* __restrict__ Bt,
    const float* __restrict__ bias, float* __restrict__ outp,
    const float* __restrict__ resid)
{
  __shared__ short As[64 * 32];
  __shared__ short Bs[128 * 32];
  int m0 = blockIdx.y << 6, n0 = blockIdx.x << 7;
  int tid = threadIdx.x;
  int lane = tid & 63, wid = tid >> 6;
  int r = lane & 15, g = lane >> 4;
  int wrow = (wid >> 1) << 5, wcol = (wid & 1) << 6;   // wave: 32 x 64
  f4 acc[2][4];
#pragma unroll
  for (int i = 0; i < 2; i++)
#pragma unroll
    for (int j = 0; j < 4; j++) {
      acc[i][j][0] = 0.f; acc[i][j][1] = 0.f;
      acc[i][j][2] = 0.f; acc[i][j][3] = 0.f;
    }
  const short* Ag = A  + ((size_t)(m0 + (tid >> 2)) << 9) + ((tid & 3) << 3);
  const short* Bg = Bt + ((size_t)(n0 + (tid >> 2)) << 9) + ((tid & 3) << 3);
  for (int k0 = 0; k0 < 512; k0 += 32) {
    __syncthreads();
    gll16(Ag + k0,            As + tid * 8);
    gll16(Bg + k0,            Bs + tid * 8);
    gll16(Bg + k0 + 64 * 512, Bs + 2048 + tid * 8);
    __syncthreads();
    bh8 a[2], b[4];
#pragma unroll
    for (int i = 0; i < 2; i++)
      a[i] = ld8(As + ((wrow + (i << 4) + r) << 5) + (g << 3));
#pragma unroll
    for (int j = 0; j < 4; j++)
      b[j] = ld8(Bs + ((wcol + (j << 4) + r) << 5) + (g << 3));
#pragma unroll
    for (int i = 0; i < 2; i++)
#pragma unroll
      for (int j = 0; j < 4; j++)
        acc[i][j] = mfma16(a[i], b[j], acc[i][j]);
  }
#pragma unroll
  for (int i = 0; i < 2; i++) {
#pragma unroll
    for (int j = 0; j < 4; j++) {
      int mm = m0 + wrow + (i << 4) + (g << 2);
      int nn = n0 + wcol + (j << 4) + r;
      int bb = nn >> 10, t = nn & 1023;
#pragma unroll
      for (int q = 0; q < 4; q++) {
        int m = mm + q;
        size_t ad = ((((size_t)bb << 9) + m) << 10) + t;
        outp[ad] = acc[i][j][q] + bias[m] + resid[ad];
      }
    }
  }
}

// ---------------------------------------------------------------------------
// Flash attention, fixed-shift softmax (no running max / rescale / shuffles).
// block = 512 (8 waves), wave w owns q-rows [16w,16w+16); chunk = 128 keys.
// q,k: [b,h,t,64] bf16; v: [b,h,64,t] bf16. Row sums via ones-MFMA.
// K staged with perm pi(c)=(c%16)*8+c/16 -> P lands in canonical key order.
// grid: (h, q-tile, b) so all 8 q-tiles of one (b,h) share an XCD's L2.
// ---------------------------------------------------------------------------
__global__ __launch_bounds__(512, 4) void attn_k(
    const short* __restrict__ qb, const short* __restrict__ kb,
    const short* __restrict__ vtb, short* __restrict__ yo)
{
  __shared__ short Ks[2 * 128 * 32];   // 16 KB [dhalf][c(perm)][32]
  __shared__ short Vs[4 * 64 * 32];    // 16 KB [ksq][d][32]
  __shared__ short Ps[4 * 128 * 32];   // 32 KB [ksq][row][32], xor-swizzled
  int h = blockIdx.x, b = blockIdx.z;
  int qt0 = blockIdx.y << 7;
  int tid = threadIdx.x, lane = tid & 63, wid = tid >> 6;
  int r = lane & 15, g = lane >> 4;
  int wbase = wid << 4;
  size_t bh = (size_t)(b * 8 + h);
  const short* Qg = qb  + ((bh << 10) + qt0) * 64;
  const short* Kg = kb  + (bh << 10) * 64;
  const short* Vg = vtb + (bh << 6) * 1024;

  bh8 qf[2];
#pragma unroll
  for (int ksd = 0; ksd < 2; ksd++)
    qf[ksd] = ld8(Qg + ((size_t)(wbase + r) << 6) + (ksd << 5) + (g << 3));

  bh8 ones;
#pragma unroll
  for (int j = 0; j < 8; j++) ones[j] = (short)0x3F80;   // bf16 1.0

  f4 oac[4], sacc;
#pragma unroll
  for (int jn = 0; jn < 4; jn++) {
    oac[jn][0] = 0.f; oac[jn][1] = 0.f; oac[jn][2] = 0.f; oac[jn][3] = 0.f;
  }
  sacc[0] = 0.f; sacc[1] = 0.f; sacc[2] = 0.f; sacc[3] = 0.f;

  const float csc = 0.18033688011112042f;   // log2(e)/8
  int u = (tid & 3) << 3;
  int c = tid >> 2;
  int pc = ((c & 15) << 3) + (c >> 4);
  int vd = (tid >> 2) & 63;
  int ksb = tid >> 8;

  for (int ck = 0; ck < 8; ck++) {
    __syncthreads();
    {
      const short* Kc = Kg + ((size_t)ck << 13);
#pragma unroll
      for (int it = 0; it < 2; it++)
        gll16(Kc + ((size_t)pc << 6) + (it << 5) + u,
              Ks + (it << 12) + (tid << 3));
      const short* Vc = Vg + (ck << 7);
#pragma unroll
      for (int it = 0; it < 2; it++)
        gll16(Vc + ((size_t)vd << 10) + (((it << 1) + ksb) << 5) + u,
              Vs + (it << 12) + (tid << 3));
    }
    __syncthreads();

    // S = Q K^T (16 MFMA); D-tile row = g*4+reg, col(perm key) = j*16+r
    f4 s[8];
#pragma unroll
    for (int j = 0; j < 8; j++) {
      s[j][0] = 0.f; s[j][1] = 0.f; s[j][2] = 0.f; s[j][3] = 0.f;
    }
#pragma unroll
    for (int ksd = 0; ksd < 2; ksd++)
#pragma unroll
      for (int j = 0; j < 8; j++)
        s[j] = mfma16(qf[ksd],
                      ld8(Ks + (ksd << 12) + (((j << 4) + r) << 5) + (g << 3)),
                      s[j]);

    // P = exp2(S*csc), no shift; pack bf16, store canonical key order
#pragma unroll
    for (int q = 0; q < 4; q++) {
      u4 pv;
      pv.x = pkbf(__builtin_amdgcn_exp2f(s[0][q] * csc),
                  __builtin_amdgcn_exp2f(s[1][q] * csc));
      pv.y = pkbf(__builtin_amdgcn_exp2f(s[2][q] * csc),
                  __builtin_amdgcn_exp2f(s[3][q] * csc));
      pv.z = pkbf(__builtin_amdgcn_exp2f(s[4][q] * csc),
                  __builtin_amdgcn_exp2f(s[5][q] * csc));
      pv.w = pkbf(__builtin_amdgcn_exp2f(s[6][q] * csc),
                  __builtin_amdgcn_exp2f(s[7][q] * csc));
      int row = wbase + (g << 2) + q;
      int ec = ((r & 3) ^ ((row >> 2) + (r >> 2))) & 3;
      *(u4*)(Ps + ((r >> 2) << 12) + (row << 5) + (ec << 3)) = pv;
    }

    // O += P V, rowsum += P 1  (waves read only their own P rows)
#pragma unroll
    for (int ks = 0; ks < 4; ks++) {
      int row = wbase + r;
      int ec = (g ^ ((row >> 2) + ks)) & 3;
      bh8 ap = ld8(Ps + (ks << 12) + (row << 5) + (ec << 3));
      sacc = mfma16(ap, ones, sacc);
#pragma unroll
      for (int jn = 0; jn < 4; jn++)
        oac[jn] = mfma16(ap,
                         ld8(Vs + (ks << 11) + (((jn << 4) + r) << 5) + (g << 3)),
                         oac[jn]);
    }
  }

  // epilogue: y[token, h*64+d]
#pragma unroll
  for (int q = 0; q < 4; q++) {
    float inv = 1.f / sacc[q];
    int trow = qt0 + wbase + (g << 2) + q;
    size_t base = (((size_t)(b << 10) + trow) << 9) + (h << 6);
#pragma unroll
    for (int jn = 0; jn < 4; jn++)
      yo[base + (jn << 4) + r] = f2bf(oac[jn][q] * inv);
  }
}

// ---------------------------------------------------------------------------
extern "C" void kernel_launch(void* const* d_in, const int* in_sizes, int n_in,
                              void* d_out, int out_size, void* d_ws, size_t ws_size,
                              hipStream_t stream)
{
  const float* q    = (const float*)d_in[0];
  const float* kv   = (const float*)d_in[1];
  const float* lnkw = (const float*)d_in[2];
  const float* lnkb = (const float*)d_in[3];
  const float* lnqw = (const float*)d_in[4];
  const float* lnqb = (const float*)d_in[5];
  const float* Wk   = (const float*)d_in[6];
  const float* bk   = (const float*)d_in[7];
  const float* Wq   = (const float*)d_in[8];
  const float* bq   = (const float*)d_in[9];
  const float* Wv   = (const float*)d_in[10];
  const float* bv   = (const float*)d_in[11];
  const float* Wp   = (const float*)d_in[12];
  const float* bp   = (const float*)d_in[13];

  char* ws = (char*)d_ws;
  const size_t SZ = (size_t)8192 * 512 * 2;      // 8 MiB per activation buffer
  short* buf0 = (short*)(ws);                    // kv_n, later reused for y
  short* qn   = (short*)(ws + SZ);
  short* kbuf = (short*)(ws + 2 * SZ);
  short* qbuf = (short*)(ws + 3 * SZ);
  short* vtb  = (short*)(ws + 4 * SZ);
  short* Wt   = (short*)(ws + 5 * SZ);           // 4 x 512x512 bf16 = 2 MiB
  if (ws_size < 5 * SZ + 4 * 512 * 512 * 2) return;   // need 42 MiB scratch

  wt_k<<<dim3(16, 16, 4), 256, 0, stream>>>(Wk, Wq, Wv, Wp, Wt);
  ln_k<<<dim3(64, 8, 2), 256, 0, stream>>>(kv, q, lnkw, lnkb, lnqw, lnqb,
                                           buf0, qn);
  gemm_qkv_k<<<dim3(64, 4, 3), 256, 0, stream>>>(buf0, qn, Wt, bk, bq, bv,
                                                 kbuf, qbuf, vtb);
  attn_k<<<dim3(8, 8, 8), 512, 0, stream>>>(qbuf, kbuf, vtb, buf0);
  gemm_proj_k<<<dim3(64, 8), 256, 0, stream>>>(Wt + (3 << 18), buf0, bp,
                                               (float*)d_out, kv);
}

// Round 3
// 176.021 us; speedup vs baseline: 1.2926x; 1.0468x over previous
//
#include <hip/hip_runtime.h>
#include <stdint.h>

#define DI static __device__ __forceinline__

typedef __attribute__((ext_vector_type(8))) short bh8;   // 8 x bf16 (4 VGPRs)
typedef __attribute__((ext_vector_type(4))) float f4;    // MFMA accumulator
typedef __attribute__((ext_vector_type(4))) unsigned int u4;

DI short f2bf(float f) {             // fp32 -> bf16 (RNE)
  unsigned u = __float_as_uint(f);
  u += 0x7fffu + ((u >> 16) & 1u);
  return (short)(u >> 16);
}

DI unsigned pkbf(float a, float b) { // [bf16(a) | bf16(b)<<16], round-half-up
  unsigned ua = __float_as_uint(a) + 0x8000u;
  unsigned ub = __float_as_uint(b) + 0x8000u;
  return __builtin_amdgcn_perm(ub, ua, 0x07060302u);
}

DI void gll16(const void* g, void* l) {  // 16B global -> LDS async
  __builtin_amdgcn_global_load_lds(
      (const __attribute__((address_space(1))) unsigned int*)g,
      (__attribute__((address_space(3))) unsigned int*)l, 16, 0, 0);
}

DI f4 mfma16(bh8 a, bh8 b, f4 c) {
  return __builtin_amdgcn_mfma_f32_16x16x32_bf16(a, b, c, 0, 0, 0);
}

DI bh8 ld8(const short* p) { return *(const bh8*)p; }

// ---------------------------------------------------------------------------
// prep_k: fused weight-transpose (roles 0..3) + LayerNorm (roles 4..5).
// grid (512, 6) x 256 threads. Role is block-uniform -> barriers legal.
// ---------------------------------------------------------------------------
__global__ __launch_bounds__(256) void prep_k(
    const float* __restrict__ kv, const float* __restrict__ qi,
    const float* __restrict__ kw, const float* __restrict__ kbv,
    const float* __restrict__ qw, const float* __restrict__ qbv,
    const float* __restrict__ Wk, const float* __restrict__ Wq,
    const float* __restrict__ Wv, const float* __restrict__ Wp,
    short* __restrict__ kvn, short* __restrict__ qn,
    short* __restrict__ Wt)
{
  __shared__ char sm[16 * 516 * 4 + 128];
  int role = blockIdx.y;
  int bx = blockIdx.x;
  int tid = threadIdx.x;

  if (role < 4) {                       // ---- weight transpose + cvt ----
    if (bx >= 256) return;
    float (*ts)[33] = (float(*)[33])sm;
    const float* w = (role == 0) ? Wk : (role == 1) ? Wq : (role == 2) ? Wv : Wp;
    short* o = Wt + ((size_t)role << 18);
    int c0 = (bx & 15) << 5, r0 = (bx >> 4) << 5;
    int tx = tid & 31, ty = tid >> 5;   // 32 x 8
#pragma unroll
    for (int k = 0; k < 32; k += 8)
      ts[ty + k][tx] = w[((size_t)(r0 + ty + k) << 9) + c0 + tx];
    __syncthreads();
#pragma unroll
    for (int k = 0; k < 32; k += 8)
      o[((size_t)(c0 + ty + k) << 9) + r0 + tx] = f2bf(ts[tx][ty + k]);
    return;
  }

  // ---- LayerNorm over C=512, fused [B,C,T] -> [token,C] transpose ----
  float (*xs)[516] = (float(*)[516])sm;
  float* smean = (float*)(sm + 16 * 516 * 4);
  float* srstd = smean + 16;
  int which = role - 4;
  const float* x = which ? qi : kv;
  const float* w = which ? qw : kw;
  const float* bb = which ? qbv : kbv;
  short* o = which ? qn : kvn;
  int b = bx >> 6;
  int t0 = (bx & 63) << 4;
  const float* xb = x + ((size_t)b << 19) + (size_t)t0;
#pragma unroll
  for (int k = 0; k < 8; k++) {
    int idx = (k << 8) + tid;            // 0..2047
    int c = idx >> 2, tt = (idx & 3) << 2;
    float4 v = *(const float4*)(xb + ((size_t)c << 10) + tt);
    xs[tt + 0][c] = v.x; xs[tt + 1][c] = v.y;
    xs[tt + 2][c] = v.z; xs[tt + 3][c] = v.w;
  }
  __syncthreads();
  {
    int t = tid >> 4, cp = tid & 15;
    float s = 0.f, s2 = 0.f;
#pragma unroll
    for (int k = 0; k < 8; k++) {
      float4 v = *(const float4*)&xs[t][(cp << 2) + (k << 6)];
      s  += v.x + v.y + v.z + v.w;
      s2 += v.x * v.x + v.y * v.y + v.z * v.z + v.w * v.w;
    }
#pragma unroll
    for (int m = 1; m < 16; m <<= 1) {
      s  += __shfl_xor(s,  m);
      s2 += __shfl_xor(s2, m);
    }
    if (cp == 0) {
      float mean = s * (1.f / 512.f);
      float var  = s2 * (1.f / 512.f) - mean * mean;
      smean[t] = mean;
      srstd[t] = rsqrtf(var + 1e-5f);
    }
  }
  __syncthreads();
#pragma unroll
  for (int k = 0; k < 8; k++) {
    int idx = (k << 8) + tid;
    int t = idx >> 7, c = (idx & 127) << 2;
    float4 v = *(const float4*)&xs[t][c];
    float4 wv = *(const float4*)(w + c);
    float4 bv4 = *(const float4*)(bb + c);
    float mu = smean[t], rs = srstd[t];
    float r0 = (v.x - mu) * rs * wv.x + bv4.x;
    float r1 = (v.y - mu) * rs * wv.y + bv4.y;
    float r2 = (v.z - mu) * rs * wv.z + bv4.z;
    float r3 = (v.w - mu) * rs * wv.w + bv4.w;
    uint2 pk; pk.x = pkbf(r0, r1); pk.y = pkbf(r2, r3);
    *(uint2*)(o + (((size_t)(b << 10) + t0 + t) << 9) + c) = pk;
  }
}

// ---------------------------------------------------------------------------
// Fused K/Q/V projection GEMM. 128x128 tile, BK=32, grid (64,4,3).
// z=0: kbuf = ln_kv @ Wk  -> bf16 [b,h,t,d]
// z=1: qbuf = ln_q  @ Wq  -> bf16 [b,h,t,d]
// z=2: vtb  = (ln_kv @ Wv)^T -> bf16 [b,h,d,t]   (A=Wv^T, B=ln_kv)
// ---------------------------------------------------------------------------
__global__ __launch_bounds__(256) void gemm_qkv_k(
    const short* __restrict__ kvn, const short* __restrict__ qn,
    const short* __restrict__ Wt,
    const float* __restrict__ bk, const float* __restrict__ bq,
    const float* __restrict__ bv,
    short* __restrict__ kbuf, short* __restrict__ qbuf,
    short* __restrict__ vtb)
{
  __shared__ short As[128 * 32];
  __shared__ short Bs[128 * 32];
  int z = blockIdx.z;
  const short* A; const short* Bt; const float* bias; short* outp;
  int m0, n0;
  if (z == 0)      { A = kvn;            Bt = Wt;             bias = bk; outp = kbuf; }
  else if (z == 1) { A = qn;             Bt = Wt + (1 << 18); bias = bq; outp = qbuf; }
  else             { A = Wt + (2 << 18); Bt = kvn;            bias = bv; outp = vtb; }
  if (z == 2) { m0 = blockIdx.y << 7; n0 = blockIdx.x << 7; }
  else        { m0 = blockIdx.x << 7; n0 = blockIdx.y << 7; }
  int tid = threadIdx.x;
  int lane = tid & 63, wid = tid >> 6;
  int r = lane & 15, g = lane >> 4;
  int wrow = (wid >> 1) << 6, wcol = (wid & 1) << 6;
  f4 acc[4][4];
#pragma unroll
  for (int i = 0; i < 4; i++)
#pragma unroll
    for (int j = 0; j < 4; j++) {
      acc[i][j][0] = 0.f; acc[i][j][1] = 0.f;
      acc[i][j][2] = 0.f; acc[i][j][3] = 0.f;
    }
  const short* Ag = A  + ((size_t)(m0 + (tid >> 2)) << 9) + ((tid & 3) << 3);
  const short* Bg = Bt + ((size_t)(n0 + (tid >> 2)) << 9) + ((tid & 3) << 3);
  short* Asl = As + tid * 8;
  short* Bsl = Bs + tid * 8;
  for (int k0 = 0; k0 < 512; k0 += 32) {
    __syncthreads();
    gll16(Ag + k0,            Asl);
    gll16(Ag + k0 + 64 * 512, Asl + 2048);
    gll16(Bg + k0,            Bsl);
    gll16(Bg + k0 + 64 * 512, Bsl + 2048);
    __syncthreads();
    bh8 a[4], b[4];
#pragma unroll
    for (int i = 0; i < 4; i++)
      a[i] = ld8(As + ((wrow + (i << 4) + r) << 5) + (g << 3));
#pragma unroll
    for (int j = 0; j < 4; j++)
      b[j] = ld8(Bs + ((wcol + (j << 4) + r) << 5) + (g << 3));
#pragma unroll
    for (int i = 0; i < 4; i++)
#pragma unroll
      for (int j = 0; j < 4; j++)
        acc[i][j] = mfma16(a[i], b[j], acc[i][j]);
  }
  // epilogue: C/D layout col = lane&15, row = (lane>>4)*4 + reg
#pragma unroll
  for (int i = 0; i < 4; i++) {
#pragma unroll
    for (int j = 0; j < 4; j++) {
      int mm = m0 + wrow + (i << 4) + (g << 2);
      int nn = n0 + wcol + (j << 4) + r;
      if (z != 2) {
        float bvv = bias[nn];
        int h = nn >> 6, d = nn & 63;
#pragma unroll
        for (int q = 0; q < 4; q++) {
          int m = mm + q;
          int bb = m >> 10, t = m & 1023;
          outp[((((size_t)(bb * 8 + h)) << 10) + t) * 64 + d] =
              f2bf(acc[i][j][q] + bvv);
        }
      } else {
        int bb = nn >> 10, t = nn & 1023;
#pragma unroll
        for (int q = 0; q < 4; q++) {
          int m = mm + q;
          int h = m >> 6, d = m & 63;
          outp[((((size_t)(bb * 8 + h)) << 6) + d) * 1024 + t] =
              f2bf(acc[i][j][q] + bias[m]);
        }
      }
    }
  }
}

// ---------------------------------------------------------------------------
// Output projection: C[c,token] = Wp^T @ y^T, 64x128 tile, grid (64,8).
// out fp32 [b,c,t] = C + bias[c] + resid.
// ---------------------------------------------------------------------------
__global__ __launch_bounds__(256) void gemm_proj_k(
    const short* __restrict__ A, const short* __restrict__ Bt,
    const float* __restrict__ bias, float* __restrict__ outp,
    const float* __restrict__ resid)
{
  __shared__ short As[64 * 32];
  __shared__ short Bs[128 * 32];
  int m0 = blockIdx.y << 6, n0 = blockIdx.x << 7;
  int tid = threadIdx.x;
  int lane = tid & 63, wid = tid >> 6;
  int r = lane & 15, g = lane >> 4;
  int wrow = (wid >> 1) << 5, wcol = (wid & 1) << 6;   // wave: 32 x 64
  f4 acc[2][4];
#pragma unroll
  for (int i = 0; i < 2; i++)
#pragma unroll
    for (int j = 0; j < 4; j++) {
      acc[i][j][0] = 0.f; acc[i][j][1] = 0.f;
      acc[i][j][2] = 0.f; acc[i][j][3] = 0.f;
    }
  const short* Ag = A  + ((size_t)(m0 + (tid >> 2)) << 9) + ((tid & 3) << 3);
  const short* Bg = Bt + ((size_t)(n0 + (tid >> 2)) << 9) + ((tid & 3) << 3);
  for (int k0 = 0; k0 < 512; k0 += 32) {
    __syncthreads();
    gll16(Ag + k0,            As + tid * 8);
    gll16(Bg + k0,            Bs + tid * 8);
    gll16(Bg + k0 + 64 * 512, Bs + 2048 + tid * 8);
    __syncthreads();
    bh8 a[2], b[4];
#pragma unroll
    for (int i = 0; i < 2; i++)
      a[i] = ld8(As + ((wrow + (i << 4) + r) << 5) + (g << 3));
#pragma unroll
    for (int j = 0; j < 4; j++)
      b[j] = ld8(Bs + ((wcol + (j << 4) + r) << 5) + (g << 3));
#pragma unroll
    for (int i = 0; i < 2; i++)
#pragma unroll
      for (int j = 0; j < 4; j++)
        acc[i][j] = mfma16(a[i], b[j], acc[i][j]);
  }
#pragma unroll
  for (int i = 0; i < 2; i++) {
#pragma unroll
    for (int j = 0; j < 4; j++) {
      int mm = m0 + wrow + (i << 4) + (g << 2);
      int nn = n0 + wcol + (j << 4) + r;
      int bb = nn >> 10, t = nn & 1023;
#pragma unroll
      for (int q = 0; q < 4; q++) {
        int m = mm + q;
        size_t ad = ((((size_t)bb << 9) + m) << 10) + t;
        outp[ad] = acc[i][j][q] + bias[m] + resid[ad];
      }
    }
  }
}

// ---------------------------------------------------------------------------
// Flash attention, fixed-shift softmax. block = 256 (4 waves); wave w owns
// 32 q-rows [32w, 32w+32) as two 16-row sub-tiles (i=0,1) -> each K/V LDS
// fragment read feeds 2 MFMA (halves per-CU LDS-pipe load vs 16-row waves).
// q,k: [b,h,t,64] bf16; v: [b,h,64,t] bf16. Row sums via ones-MFMA.
// K staged with perm pi(c)=(c%16)*8+c/16 -> P lands in canonical key order.
// ---------------------------------------------------------------------------
__global__ __launch_bounds__(256, 2) void attn_k(
    const short* __restrict__ qb, const short* __restrict__ kb,
    const short* __restrict__ vtb, short* __restrict__ yo)
{
  __shared__ short Ks[2 * 128 * 32];   // 16 KB [dhalf][c(perm)][32]
  __shared__ short Vs[4 * 64 * 32];    // 16 KB [ksq][d][32]
  __shared__ short Ps[4 * 128 * 32];   // 32 KB [ksq][row][32], xor-swizzled
  int h = blockIdx.x, b = blockIdx.z;
  int qt0 = blockIdx.y << 7;
  int tid = threadIdx.x, lane = tid & 63, wid = tid >> 6;
  int r = lane & 15, g = lane >> 4;
  int wbase = wid << 5;
  size_t bh = (size_t)(b * 8 + h);
  const short* Qg = qb  + ((bh << 10) + qt0) * 64;
  const short* Kg = kb  + (bh << 10) * 64;
  const short* Vg = vtb + (bh << 6) * 1024;

  bh8 qf[2][2];
#pragma unroll
  for (int i = 0; i < 2; i++)
#pragma unroll
    for (int ksd = 0; ksd < 2; ksd++)
      qf[i][ksd] = ld8(Qg + ((size_t)(wbase + (i << 4) + r) << 6) +
                       (ksd << 5) + (g << 3));

  bh8 ones;
#pragma unroll
  for (int j = 0; j < 8; j++) ones[j] = (short)0x3F80;   // bf16 1.0

  f4 oac[2][4], sacc[2];
#pragma unroll
  for (int i = 0; i < 2; i++) {
#pragma unroll
    for (int jn = 0; jn < 4; jn++) {
      oac[i][jn][0] = 0.f; oac[i][jn][1] = 0.f;
      oac[i][jn][2] = 0.f; oac[i][jn][3] = 0.f;
    }
    sacc[i][0] = 0.f; sacc[i][1] = 0.f; sacc[i][2] = 0.f; sacc[i][3] = 0.f;
  }

  const float csc = 0.18033688011112042f;   // log2(e)/8
  int u = (tid & 3) << 3;

  for (int ck = 0; ck < 8; ck++) {
    __syncthreads();
    {
      const short* Kc = Kg + ((size_t)ck << 13);
#pragma unroll
      for (int it = 0; it < 4; it++) {
        int c = ((it & 1) << 6) + (tid >> 2);
        int pc = ((c & 15) << 3) + (c >> 4);
        gll16(Kc + ((size_t)pc << 6) + ((it >> 1) << 5) + u,
              Ks + (it << 11) + (tid << 3));
      }
      const short* Vc = Vg + (ck << 7);
#pragma unroll
      for (int it = 0; it < 4; it++)
        gll16(Vc + ((size_t)(tid >> 2) << 10) + (it << 5) + u,
              Vs + (it << 11) + (tid << 3));
    }
    __syncthreads();

    // S = Q K^T : 16 K-fragment reads feed 32 MFMA
    f4 s[2][8];
#pragma unroll
    for (int i = 0; i < 2; i++)
#pragma unroll
      for (int j = 0; j < 8; j++) {
        s[i][j][0] = 0.f; s[i][j][1] = 0.f;
        s[i][j][2] = 0.f; s[i][j][3] = 0.f;
      }
#pragma unroll
    for (int ksd = 0; ksd < 2; ksd++)
#pragma unroll
      for (int j = 0; j < 8; j++) {
        bh8 bk8 = ld8(Ks + (ksd << 12) + (((j << 4) + r) << 5) + (g << 3));
#pragma unroll
        for (int i = 0; i < 2; i++)
          s[i][j] = mfma16(qf[i][ksd], bk8, s[i][j]);
      }

    // P = exp2(S*csc); pack bf16; store to Ps in canonical key order
#pragma unroll
    for (int i = 0; i < 2; i++)
#pragma unroll
      for (int q = 0; q < 4; q++) {
        u4 pv;
        pv.x = pkbf(__builtin_amdgcn_exp2f(s[i][0][q] * csc),
                    __builtin_amdgcn_exp2f(s[i][1][q] * csc));
        pv.y = pkbf(__builtin_amdgcn_exp2f(s[i][2][q] * csc),
                    __builtin_amdgcn_exp2f(s[i][3][q] * csc));
        pv.z = pkbf(__builtin_amdgcn_exp2f(s[i][4][q] * csc),
                    __builtin_amdgcn_exp2f(s[i][5][q] * csc));
        pv.w = pkbf(__builtin_amdgcn_exp2f(s[i][6][q] * csc),
                    __builtin_amdgcn_exp2f(s[i][7][q] * csc));
        int row = wbase + (i << 4) + (g << 2) + q;
        int ec = ((r & 3) ^ ((row >> 2) + (r >> 2))) & 3;
        *(u4*)(Ps + ((r >> 2) << 12) + (row << 5) + (ec << 3)) = pv;
      }

    // O += P V, rowsum += P 1  (wave reads only rows it wrote)
#pragma unroll
    for (int ks = 0; ks < 4; ks++) {
      bh8 ap[2];
#pragma unroll
      for (int i = 0; i < 2; i++) {
        int row = wbase + (i << 4) + r;
        int ec = (g ^ ((row >> 2) + ks)) & 3;
        ap[i] = ld8(Ps + (ks << 12) + (row << 5) + (ec << 3));
        sacc[i] = mfma16(ap[i], ones, sacc[i]);
      }
#pragma unroll
      for (int jn = 0; jn < 4; jn++) {
        bh8 bv8 = ld8(Vs + (ks << 11) + (((jn << 4) + r) << 5) + (g << 3));
#pragma unroll
        for (int i = 0; i < 2; i++)
          oac[i][jn] = mfma16(ap[i], bv8, oac[i][jn]);
      }
    }
  }

  // epilogue: y[token, h*64+d]
#pragma unroll
  for (int i = 0; i < 2; i++)
#pragma unroll
    for (int q = 0; q < 4; q++) {
      float inv = 1.f / sacc[i][q];
      int trow = qt0 + wbase + (i << 4) + (g << 2) + q;
      size_t base = (((size_t)(b << 10) + trow) << 9) + (h << 6);
#pragma unroll
      for (int jn = 0; jn < 4; jn++)
        yo[base + (jn << 4) + r] = f2bf(oac[i][jn][q] * inv);
    }
}

// ---------------------------------------------------------------------------
extern "C" void kernel_launch(void* const* d_in, const int* in_sizes, int n_in,
                              void* d_out, int out_size, void* d_ws, size_t ws_size,
                              hipStream_t stream)
{
  const float* q    = (const float*)d_in[0];
  const float* kv   = (const float*)d_in[1];
  const float* lnkw = (const float*)d_in[2];
  const float* lnkb = (const float*)d_in[3];
  const float* lnqw = (const float*)d_in[4];
  const float* lnqb = (const float*)d_in[5];
  const float* Wk   = (const float*)d_in[6];
  const float* bk   = (const float*)d_in[7];
  const float* Wq   = (const float*)d_in[8];
  const float* bq   = (const float*)d_in[9];
  const float* Wv   = (const float*)d_in[10];
  const float* bv   = (const float*)d_in[11];
  const float* Wp   = (const float*)d_in[12];
  const float* bp   = (const float*)d_in[13];

  char* ws = (char*)d_ws;
  const size_t SZ = (size_t)8192 * 512 * 2;      // 8 MiB per activation buffer
  short* buf0 = (short*)(ws);                    // kv_n, later reused for y
  short* qn   = (short*)(ws + SZ);
  short* kbuf = (short*)(ws + 2 * SZ);
  short* qbuf = (short*)(ws + 3 * SZ);
  short* vtb  = (short*)(ws + 4 * SZ);
  short* Wt   = (short*)(ws + 5 * SZ);           // 4 x 512x512 bf16 = 2 MiB
  if (ws_size < 5 * SZ + 4 * 512 * 512 * 2) return;   // need 42 MiB scratch

  prep_k<<<dim3(512, 6), 256, 0, stream>>>(kv, q, lnkw, lnkb, lnqw, lnqb,
                                           Wk, Wq, Wv, Wp, buf0, qn, Wt);
  gemm_qkv_k<<<dim3(64, 4, 3), 256, 0, stream>>>(buf0, qn, Wt, bk, bq, bv,
                                                 kbuf, qbuf, vtb);
  attn_k<<<dim3(8, 8, 8), 256, 0, stream>>>(qbuf, kbuf, vtb, buf0);
  gemm_proj_k<<<dim3(64, 8), 256, 0, stream>>>(Wt + (3 << 18), buf0, bp,
                                               (float*)d_out, kv);
}

// Round 4
// 172.153 us; speedup vs baseline: 1.3216x; 1.0225x over previous
//
#include <hip/hip_runtime.h>
#include <stdint.h>

#define DI static __device__ __forceinline__

typedef __attribute__((ext_vector_type(8))) short bh8;   // 8 x bf16 (4 VGPRs)
typedef __attribute__((ext_vector_type(4))) float f4;    // MFMA accumulator
typedef __attribute__((ext_vector_type(4))) unsigned int u4;

DI short f2bf(float f) {             // fp32 -> bf16 (RNE)
  unsigned u = __float_as_uint(f);
  u += 0x7fffu + ((u >> 16) & 1u);
  return (short)(u >> 16);
}

DI unsigned pkbf(float a, float b) { // [bf16(a) | bf16(b)<<16], round-half-up
  unsigned ua = __float_as_uint(a) + 0x8000u;
  unsigned ub = __float_as_uint(b) + 0x8000u;
  return __builtin_amdgcn_perm(ub, ua, 0x07060302u);
}

DI void gll16(const void* g, void* l) {  // 16B global -> LDS async
  __builtin_amdgcn_global_load_lds(
      (const __attribute__((address_space(1))) unsigned int*)g,
      (__attribute__((address_space(3))) unsigned int*)l, 16, 0, 0);
}

DI f4 mfma16(bh8 a, bh8 b, f4 c) {
  return __builtin_amdgcn_mfma_f32_16x16x32_bf16(a, b, c, 0, 0, 0);
}

DI bh8 ld8(const short* p) { return *(const bh8*)p; }

// ---------------------------------------------------------------------------
// prep_k: fused weight-transpose (roles 0..3) + LayerNorm (roles 4..5).
// grid (512, 6) x 256 threads. Role is block-uniform -> barriers legal.
// ---------------------------------------------------------------------------
__global__ __launch_bounds__(256) void prep_k(
    const float* __restrict__ kv, const float* __restrict__ qi,
    const float* __restrict__ kw, const float* __restrict__ kbv,
    const float* __restrict__ qw, const float* __restrict__ qbv,
    const float* __restrict__ Wk, const float* __restrict__ Wq,
    const float* __restrict__ Wv, const float* __restrict__ Wp,
    short* __restrict__ kvn, short* __restrict__ qn,
    short* __restrict__ Wt)
{
  __shared__ char sm[16 * 516 * 4 + 128];
  int role = blockIdx.y;
  int bx = blockIdx.x;
  int tid = threadIdx.x;

  if (role < 4) {                       // ---- weight transpose + cvt ----
    if (bx >= 256) return;
    float (*ts)[33] = (float(*)[33])sm;
    const float* w = (role == 0) ? Wk : (role == 1) ? Wq : (role == 2) ? Wv : Wp;
    short* o = Wt + ((size_t)role << 18);
    int c0 = (bx & 15) << 5, r0 = (bx >> 4) << 5;
    int tx = tid & 31, ty = tid >> 5;   // 32 x 8
#pragma unroll
    for (int k = 0; k < 32; k += 8)
      ts[ty + k][tx] = w[((size_t)(r0 + ty + k) << 9) + c0 + tx];
    __syncthreads();
#pragma unroll
    for (int k = 0; k < 32; k += 8)
      o[((size_t)(c0 + ty + k) << 9) + r0 + tx] = f2bf(ts[tx][ty + k]);
    return;
  }

  // ---- LayerNorm over C=512, fused [B,C,T] -> [token,C] transpose ----
  float (*xs)[516] = (float(*)[516])sm;
  float* smean = (float*)(sm + 16 * 516 * 4);
  float* srstd = smean + 16;
  int which = role - 4;
  const float* x = which ? qi : kv;
  const float* w = which ? qw : kw;
  const float* bb = which ? qbv : kbv;
  short* o = which ? qn : kvn;
  int b = bx >> 6;
  int t0 = (bx & 63) << 4;
  const float* xb = x + ((size_t)b << 19) + (size_t)t0;
#pragma unroll
  for (int k = 0; k < 8; k++) {
    int idx = (k << 8) + tid;            // 0..2047
    int c = idx >> 2, tt = (idx & 3) << 2;
    float4 v = *(const float4*)(xb + ((size_t)c << 10) + tt);
    xs[tt + 0][c] = v.x; xs[tt + 1][c] = v.y;
    xs[tt + 2][c] = v.z; xs[tt + 3][c] = v.w;
  }
  __syncthreads();
  {
    int t = tid >> 4, cp = tid & 15;
    float s = 0.f, s2 = 0.f;
#pragma unroll
    for (int k = 0; k < 8; k++) {
      float4 v = *(const float4*)&xs[t][(cp << 2) + (k << 6)];
      s  += v.x + v.y + v.z + v.w;
      s2 += v.x * v.x + v.y * v.y + v.z * v.z + v.w * v.w;
    }
#pragma unroll
    for (int m = 1; m < 16; m <<= 1) {
      s  += __shfl_xor(s,  m);
      s2 += __shfl_xor(s2, m);
    }
    if (cp == 0) {
      float mean = s * (1.f / 512.f);
      float var  = s2 * (1.f / 512.f) - mean * mean;
      smean[t] = mean;
      srstd[t] = rsqrtf(var + 1e-5f);
    }
  }
  __syncthreads();
#pragma unroll
  for (int k = 0; k < 8; k++) {
    int idx = (k << 8) + tid;
    int t = idx >> 7, c = (idx & 127) << 2;
    float4 v = *(const float4*)&xs[t][c];
    float4 wv = *(const float4*)(w + c);
    float4 bv4 = *(const float4*)(bb + c);
    float mu = smean[t], rs = srstd[t];
    float r0 = (v.x - mu) * rs * wv.x + bv4.x;
    float r1 = (v.y - mu) * rs * wv.y + bv4.y;
    float r2 = (v.z - mu) * rs * wv.z + bv4.z;
    float r3 = (v.w - mu) * rs * wv.w + bv4.w;
    uint2 pk; pk.x = pkbf(r0, r1); pk.y = pkbf(r2, r3);
    *(uint2*)(o + (((size_t)(b << 10) + t0 + t) << 9) + c) = pk;
  }
}

// ---------------------------------------------------------------------------
// Fused K/Q/V projection GEMM. 128x128 tile, BK=64, grid (64,4,3).
// LDS 16B-chunk c of row R stored at c ^ (R&7)  -> 2-way (free) bank pattern
// for both the ds_read_b128 fragments and the DMA staging.
// z=0: kbuf = ln_kv @ Wk  -> bf16 [b,h,t,d]
// z=1: qbuf = ln_q  @ Wq  -> bf16 [b,h,t,d]
// z=2: vtb  = (ln_kv @ Wv)^T -> bf16 [b,h,d,t]   (A=Wv^T, B=ln_kv)
// ---------------------------------------------------------------------------
__global__ __launch_bounds__(256, 3) void gemm_qkv_k(
    const short* __restrict__ kvn, const short* __restrict__ qn,
    const short* __restrict__ Wt,
    const float* __restrict__ bk, const float* __restrict__ bq,
    const float* __restrict__ bv,
    short* __restrict__ kbuf, short* __restrict__ qbuf,
    short* __restrict__ vtb)
{
  __shared__ short As[128 * 64];   // 16 KB
  __shared__ short Bs[128 * 64];   // 16 KB
  int z = blockIdx.z;
  const short* A; const short* Bt; const float* bias; short* outp;
  int m0, n0;
  if (z == 0)      { A = kvn;            Bt = Wt;             bias = bk; outp = kbuf; }
  else if (z == 1) { A = qn;             Bt = Wt + (1 << 18); bias = bq; outp = qbuf; }
  else             { A = Wt + (2 << 18); Bt = kvn;            bias = bv; outp = vtb; }
  if (z == 2) { m0 = blockIdx.y << 7; n0 = blockIdx.x << 7; }
  else        { m0 = blockIdx.x << 7; n0 = blockIdx.y << 7; }
  int tid = threadIdx.x;
  int lane = tid & 63, wid = tid >> 6;
  int r = lane & 15, g = lane >> 4;
  int wrow = (wid >> 1) << 6, wcol = (wid & 1) << 6;
  f4 acc[4][4];
#pragma unroll
  for (int i = 0; i < 4; i++)
#pragma unroll
    for (int j = 0; j < 4; j++) {
      acc[i][j][0] = 0.f; acc[i][j][1] = 0.f;
      acc[i][j][2] = 0.f; acc[i][j][3] = 0.f;
    }
  for (int k0 = 0; k0 < 512; k0 += 64) {
    __syncthreads();
#pragma unroll
    for (int it = 0; it < 4; it++) {
      int n = (it << 8) + tid;           // 16B-unit index, lane-contiguous
      int row = n >> 3;
      int c = (n & 7) ^ (row & 7);       // source chunk for swizzled slot
      gll16(A  + ((size_t)(m0 + row) << 9) + k0 + (c << 3), As + (n << 3));
      gll16(Bt + ((size_t)(n0 + row) << 9) + k0 + (c << 3), Bs + (n << 3));
    }
    __syncthreads();
    bh8 a[2][4], b[2][4];
#pragma unroll
    for (int ks = 0; ks < 2; ks++) {
#pragma unroll
      for (int i = 0; i < 4; i++) {
        int R = wrow + (i << 4) + r;
        a[ks][i] = ld8(As + (R << 6) + ((((ks << 2) + g) ^ (R & 7)) << 3));
      }
#pragma unroll
      for (int j = 0; j < 4; j++) {
        int R = wcol + (j << 4) + r;
        b[ks][j] = ld8(Bs + (R << 6) + ((((ks << 2) + g) ^ (R & 7)) << 3));
      }
    }
#pragma unroll
    for (int ks = 0; ks < 2; ks++)
#pragma unroll
      for (int i = 0; i < 4; i++)
#pragma unroll
        for (int j = 0; j < 4; j++)
          acc[i][j] = mfma16(a[ks][i], b[ks][j], acc[i][j]);
  }
  // epilogue: C/D layout col = lane&15, row = (lane>>4)*4 + reg
#pragma unroll
  for (int i = 0; i < 4; i++) {
#pragma unroll
    for (int j = 0; j < 4; j++) {
      int mm = m0 + wrow + (i << 4) + (g << 2);
      int nn = n0 + wcol + (j << 4) + r;
      if (z != 2) {
        float bvv = bias[nn];
        int h = nn >> 6, d = nn & 63;
#pragma unroll
        for (int q = 0; q < 4; q++) {
          int m = mm + q;
          int bb = m >> 10, t = m & 1023;
          outp[((((size_t)(bb * 8 + h)) << 10) + t) * 64 + d] =
              f2bf(acc[i][j][q] + bvv);
        }
      } else {
        int bb = nn >> 10, t = nn & 1023;
#pragma unroll
        for (int q = 0; q < 4; q++) {
          int m = mm + q;
          int h = m >> 6, d = m & 63;
          outp[((((size_t)(bb * 8 + h)) << 6) + d) * 1024 + t] =
              f2bf(acc[i][j][q] + bias[m]);
        }
      }
    }
  }
}

// ---------------------------------------------------------------------------
// Output projection: C[c,token] = Wp^T @ y^T, 64x128 tile, BK=64, grid (64,8).
// Same xor bank swizzle as gemm_qkv_k. out fp32 [b,c,t] = C + bias[c] + resid.
// ---------------------------------------------------------------------------
__global__ __launch_bounds__(256, 2) void gemm_proj_k(
    const short* __restrict__ A, const short* __restrict__ Bt,
    const float* __restrict__ bias, float* __restrict__ outp,
    const float* __restrict__ resid)
{
  __shared__ short As[64 * 64];    // 8 KB
  __shared__ short Bs[128 * 64];   // 16 KB
  int m0 = blockIdx.y << 6, n0 = blockIdx.x << 7;
  int tid = threadIdx.x;
  int lane = tid & 63, wid = tid >> 6;
  int r = lane & 15, g = lane >> 4;
  int wrow = (wid >> 1) << 5, wcol = (wid & 1) << 6;   // wave: 32 x 64
  f4 acc[2][4];
#pragma unroll
  for (int i = 0; i < 2; i++)
#pragma unroll
    for (int j = 0; j < 4; j++) {
      acc[i][j][0] = 0.f; acc[i][j][1] = 0.f;
      acc[i][j][2] = 0.f; acc[i][j][3] = 0.f;
    }
  for (int k0 = 0; k0 < 512; k0 += 64) {
    __syncthreads();
#pragma unroll
    for (int it = 0; it < 2; it++) {     // As: 512 units
      int n = (it << 8) + tid;
      int row = n >> 3;
      int c = (n & 7) ^ (row & 7);
      gll16(A + ((size_t)(m0 + row) << 9) + k0 + (c << 3), As + (n << 3));
    }
#pragma unroll
    for (int it = 0; it < 4; it++) {     // Bs: 1024 units
      int n = (it << 8) + tid;
      int row = n >> 3;
      int c = (n & 7) ^ (row & 7);
      gll16(Bt + ((size_t)(n0 + row) << 9) + k0 + (c << 3), Bs + (n << 3));
    }
    __syncthreads();
    bh8 a[2][2], b[2][4];
#pragma unroll
    for (int ks = 0; ks < 2; ks++) {
#pragma unroll
      for (int i = 0; i < 2; i++) {
        int R = wrow + (i << 4) + r;
        a[ks][i] = ld8(As + (R << 6) + ((((ks << 2) + g) ^ (R & 7)) << 3));
      }
#pragma unroll
      for (int j = 0; j < 4; j++) {
        int R = wcol + (j << 4) + r;
        b[ks][j] = ld8(Bs + (R << 6) + ((((ks << 2) + g) ^ (R & 7)) << 3));
      }
    }
#pragma unroll
    for (int ks = 0; ks < 2; ks++)
#pragma unroll
      for (int i = 0; i < 2; i++)
#pragma unroll
        for (int j = 0; j < 4; j++)
          acc[i][j] = mfma16(a[ks][i], b[ks][j], acc[i][j]);
  }
#pragma unroll
  for (int i = 0; i < 2; i++) {
#pragma unroll
    for (int j = 0; j < 4; j++) {
      int mm = m0 + wrow + (i << 4) + (g << 2);
      int nn = n0 + wcol + (j << 4) + r;
      int bb = nn >> 10, t = nn & 1023;
#pragma unroll
      for (int q = 0; q < 4; q++) {
        int m = mm + q;
        size_t ad = ((((size_t)bb << 9) + m) << 10) + t;
        outp[ad] = acc[i][j][q] + bias[m] + resid[ad];
      }
    }
  }
}

// ---------------------------------------------------------------------------
// Flash attention, fixed-shift softmax. block = 256 (4 waves); wave w owns
// 32 q-rows [32w, 32w+32) as two 16-row sub-tiles (i=0,1) -> each K/V LDS
// fragment read feeds 2 MFMA. q,k: [b,h,t,64] bf16; v: [b,h,64,t] bf16.
// Row sums via ones-MFMA. K staged with perm pi(c)=(c%16)*8+c/16 -> P lands
// in canonical key order. grid (h, qtile, b): qtile-stride 8 = same XCD.
// ---------------------------------------------------------------------------
__global__ __launch_bounds__(256, 2) void attn_k(
    const short* __restrict__ qb, const short* __restrict__ kb,
    const short* __restrict__ vtb, short* __restrict__ yo)
{
  __shared__ short Ks[2 * 128 * 32];   // 16 KB [dhalf][c(perm)][32]
  __shared__ short Vs[4 * 64 * 32];    // 16 KB [ksq][d][32]
  __shared__ short Ps[4 * 128 * 32];   // 32 KB [ksq][row][32], xor-swizzled
  int h = blockIdx.x, b = blockIdx.z;
  int qt0 = blockIdx.y << 7;
  int tid = threadIdx.x, lane = tid & 63, wid = tid >> 6;
  int r = lane & 15, g = lane >> 4;
  int wbase = wid << 5;
  size_t bh = (size_t)(b * 8 + h);
  const short* Qg = qb  + ((bh << 10) + qt0) * 64;
  const short* Kg = kb  + (bh << 10) * 64;
  const short* Vg = vtb + (bh << 6) * 1024;

  bh8 qf[2][2];
#pragma unroll
  for (int i = 0; i < 2; i++)
#pragma unroll
    for (int ksd = 0; ksd < 2; ksd++)
      qf[i][ksd] = ld8(Qg + ((size_t)(wbase + (i << 4) + r) << 6) +
                       (ksd << 5) + (g << 3));

  bh8 ones;
#pragma unroll
  for (int j = 0; j < 8; j++) ones[j] = (short)0x3F80;   // bf16 1.0

  f4 oac[2][4], sacc[2];
#pragma unroll
  for (int i = 0; i < 2; i++) {
#pragma unroll
    for (int jn = 0; jn < 4; jn++) {
      oac[i][jn][0] = 0.f; oac[i][jn][1] = 0.f;
      oac[i][jn][2] = 0.f; oac[i][jn][3] = 0.f;
    }
    sacc[i][0] = 0.f; sacc[i][1] = 0.f; sacc[i][2] = 0.f; sacc[i][3] = 0.f;
  }

  const float csc = 0.18033688011112042f;   // log2(e)/8
  int u = (tid & 3) << 3;

  for (int ck = 0; ck < 8; ck++) {
    __syncthreads();
    {
      const short* Kc = Kg + ((size_t)ck << 13);
#pragma unroll
      for (int it = 0; it < 4; it++) {
        int c = ((it & 1) << 6) + (tid >> 2);
        int pc = ((c & 15) << 3) + (c >> 4);
        gll16(Kc + ((size_t)pc << 6) + ((it >> 1) << 5) + u,
              Ks + (it << 11) + (tid << 3));
      }
      const short* Vc = Vg + (ck << 7);
#pragma unroll
      for (int it = 0; it < 4; it++)
        gll16(Vc + ((size_t)(tid >> 2) << 10) + (it << 5) + u,
              Vs + (it << 11) + (tid << 3));
    }
    __syncthreads();

    // S = Q K^T : 16 K-fragment reads feed 32 MFMA
    f4 s[2][8];
#pragma unroll
    for (int i = 0; i < 2; i++)
#pragma unroll
      for (int j = 0; j < 8; j++) {
        s[i][j][0] = 0.f; s[i][j][1] = 0.f;
        s[i][j][2] = 0.f; s[i][j][3] = 0.f;
      }
#pragma unroll
    for (int ksd = 0; ksd < 2; ksd++)
#pragma unroll
      for (int j = 0; j < 8; j++) {
        bh8 bk8 = ld8(Ks + (ksd << 12) + (((j << 4) + r) << 5) + (g << 3));
#pragma unroll
        for (int i = 0; i < 2; i++)
          s[i][j] = mfma16(qf[i][ksd], bk8, s[i][j]);
      }

    // P = exp2(S*csc); pack bf16; store to Ps in canonical key order
#pragma unroll
    for (int i = 0; i < 2; i++)
#pragma unroll
      for (int q = 0; q < 4; q++) {
        u4 pv;
        pv.x = pkbf(__builtin_amdgcn_exp2f(s[i][0][q] * csc),
                    __builtin_amdgcn_exp2f(s[i][1][q] * csc));
        pv.y = pkbf(__builtin_amdgcn_exp2f(s[i][2][q] * csc),
                    __builtin_amdgcn_exp2f(s[i][3][q] * csc));
        pv.z = pkbf(__builtin_amdgcn_exp2f(s[i][4][q] * csc),
                    __builtin_amdgcn_exp2f(s[i][5][q] * csc));
        pv.w = pkbf(__builtin_amdgcn_exp2f(s[i][6][q] * csc),
                    __builtin_amdgcn_exp2f(s[i][7][q] * csc));
        int row = wbase + (i << 4) + (g << 2) + q;
        int ec = ((r & 3) ^ ((row >> 2) + (r >> 2))) & 3;
        *(u4*)(Ps + ((r >> 2) << 12) + (row << 5) + (ec << 3)) = pv;
      }

    // O += P V, rowsum += P 1  (wave reads only rows it wrote)
#pragma unroll
    for (int ks = 0; ks < 4; ks++) {
      bh8 ap[2];
#pragma unroll
      for (int i = 0; i < 2; i++) {
        int row = wbase + (i << 4) + r;
        int ec = (g ^ ((row >> 2) + ks)) & 3;
        ap[i] = ld8(Ps + (ks << 12) + (row << 5) + (ec << 3));
        sacc[i] = mfma16(ap[i], ones, sacc[i]);
      }
#pragma unroll
      for (int jn = 0; jn < 4; jn++) {
        bh8 bv8 = ld8(Vs + (ks << 11) + (((jn << 4) + r) << 5) + (g << 3));
#pragma unroll
        for (int i = 0; i < 2; i++)
          oac[i][jn] = mfma16(ap[i], bv8, oac[i][jn]);
      }
    }
  }

  // epilogue: y[token, h*64+d]
#pragma unroll
  for (int i = 0; i < 2; i++)
#pragma unroll
    for (int q = 0; q < 4; q++) {
      float inv = 1.f / sacc[i][q];
      int trow = qt0 + wbase + (i << 4) + (g << 2) + q;
      size_t base = (((size_t)(b << 10) + trow) << 9) + (h << 6);
#pragma unroll
      for (int jn = 0; jn < 4; jn++)
        yo[base + (jn << 4) + r] = f2bf(oac[i][jn][q] * inv);
    }
}

// ---------------------------------------------------------------------------
extern "C" void kernel_launch(void* const* d_in, const int* in_sizes, int n_in,
                              void* d_out, int out_size, void* d_ws, size_t ws_size,
                              hipStream_t stream)
{
  const float* q    = (const float*)d_in[0];
  const float* kv   = (const float*)d_in[1];
  const float* lnkw = (const float*)d_in[2];
  const float* lnkb = (const float*)d_in[3];
  const float* lnqw = (const float*)d_in[4];
  const float* lnqb = (const float*)d_in[5];
  const float* Wk   = (const float*)d_in[6];
  const float* bk   = (const float*)d_in[7];
  const float* Wq   = (const float*)d_in[8];
  const float* bq   = (const float*)d_in[9];
  const float* Wv   = (const float*)d_in[10];
  const float* bv   = (const float*)d_in[11];
  const float* Wp   = (const float*)d_in[12];
  const float* bp   = (const float*)d_in[13];

  char* ws = (char*)d_ws;
  const size_t SZ = (size_t)8192 * 512 * 2;      // 8 MiB per activation buffer
  short* buf0 = (short*)(ws);                    // kv_n, later reused for y
  short* qn   = (short*)(ws + SZ);
  short* kbuf = (short*)(ws + 2 * SZ);
  short* qbuf = (short*)(ws + 3 * SZ);
  short* vtb  = (short*)(ws + 4 * SZ);
  short* Wt   = (short*)(ws + 5 * SZ);           // 4 x 512x512 bf16 = 2 MiB
  if (ws_size < 5 * SZ + 4 * 512 * 512 * 2) return;   // need 42 MiB scratch

  prep_k<<<dim3(512, 6), 256, 0, stream>>>(kv, q, lnkw, lnkb, lnqw, lnqb,
                                           Wk, Wq, Wv, Wp, buf0, qn, Wt);
  gemm_qkv_k<<<dim3(64, 4, 3), 256, 0, stream>>>(buf0, qn, Wt, bk, bq, bv,
                                                 kbuf, qbuf, vtb);
  attn_k<<<dim3(8, 8, 8), 256, 0, stream>>>(qbuf, kbuf, vtb, buf0);
  gemm_proj_k<<<dim3(64, 8), 256, 0, stream>>>(Wt + (3 << 18), buf0, bp,
                                               (float*)d_out, kv);
}